// Round 1
// baseline (671.163 us; speedup 1.0000x reference)
//
#include <hip/hip_runtime.h>

typedef _Float16 f16;
typedef __attribute__((ext_vector_type(8))) _Float16 f16x8;
typedef __attribute__((ext_vector_type(4))) _Float16 f16x4;
typedef __attribute__((ext_vector_type(4))) float    f32x4;

#define MFMA(a,b,c) __builtin_amdgcn_mfma_f32_16x16x32_f16(a,b,c,0,0,0)

// problem constants
constexpr int Bc = 2, Nc = 65536, Cc = 256, Hc = 8;
constexpr int CHUNK = 512;                 // tokens per block: 4 m0-tiles of 128
constexpr int LDT = 136;                   // fxT/wT transpose-buffer stride (f16)

// ---- workspace layout (bytes) ----
// 0      : Tg    float[16*4096] (262144)
// 262144 : normg float[16*64]   (4096)
// 266240 : WC    f16[8*128*256] (524288)  [h][n][k]; n 0..63 = Wfx cols, 64..127 = Wxs = Wx_h@Ws
// 790528 : bsp   float[8*64]    (2048)    folded slice bias: bx_h@Ws + bsl

__device__ __forceinline__ f32x4 splat4(float v) { f32x4 r; r.x=v; r.y=v; r.z=v; r.w=v; return r; }
__device__ __forceinline__ f16x8 pack8(float4 a, float4 b) {
  f16x8 r = { (f16)a.x,(f16)a.y,(f16)a.z,(f16)a.w,(f16)b.x,(f16)b.y,(f16)b.z,(f16)b.w };
  return r;
}

// prep: 97 blocks. (unchanged)
__global__ void prep_a(const float* __restrict__ Wx, const float* __restrict__ Wfx,
                       const float* __restrict__ Wsl, const float* __restrict__ bx,
                       const float* __restrict__ bsl, f16* __restrict__ WC,
                       float* __restrict__ bsp) {
  __shared__ float tile[64][72];
  const int b = blockIdx.x, t = threadIdx.x;
  if (b < 32) {                            // transpose Wfx tile (k0..+64) x (c0..+64)
    const int k0 = (b & 3) * 64, c0 = (b >> 2) * 64;
    const int r = t >> 4, c4 = (t & 15) * 4;
    #pragma unroll
    for (int i = 0; i < 4; ++i) {
      float4 v = *(const float4*)&Wfx[(size_t)(k0 + r + i*16)*512 + c0 + c4];
      tile[r + i*16][c4] = v.x; tile[r + i*16][c4+1] = v.y;
      tile[r + i*16][c4+2] = v.z; tile[r + i*16][c4+3] = v.w;
    }
    __syncthreads();
    const int cl = t >> 2, kq = t & 3;
    const int col = c0 + cl, h = col >> 6, n = col & 63;
    f16 tmp[16];
    #pragma unroll
    for (int j = 0; j < 16; ++j) tmp[j] = (f16)tile[kq*16 + j][cl];
    f16* dst = WC + (size_t)(h*128 + n)*256 + k0 + kq*16;
    *(f16x8*)dst       = *(f16x8*)&tmp[0];
    *(f16x8*)(dst + 8) = *(f16x8*)&tmp[8];
  } else if (b < 96) {                     // Wxs rows
    const int bb = b - 32;
    const int h = bb >> 3, k0 = (bb & 7) * 32;
    const int k = t & 31, sq = t >> 5;     // 8 s-values per thread
    float accs[8];
    #pragma unroll
    for (int j = 0; j < 8; ++j) accs[j] = 0.f;
    for (int d = 0; d < 64; ++d) {
      float a = Wx[(size_t)(k0 + k)*512 + h*64 + d];
      #pragma unroll
      for (int j = 0; j < 8; ++j) accs[j] += a * Wsl[d*64 + sq*8 + j];
    }
    #pragma unroll
    for (int j = 0; j < 8; ++j)
      WC[(size_t)(h*128 + 64 + sq*8 + j)*256 + k0 + k] = (f16)accs[j];
  } else {                                 // bsp[h][s]
    for (int u = t; u < 512; u += 256) {
      int h = u >> 6, s = u & 63;
      float a = bsl[s];
      for (int d = 0; d < 64; ++d) a += bx[h*64 + d] * Wsl[d*64 + s];
      bsp[h*64 + s] = a;
    }
  }
}

// Phase A now loads MFMA fragments DIRECTLY from global (x: f32->cvt, WC: f16
// already in [n][k] fragment layout) — no LDS staging, no barriers in the K-loop.
// Wave grid is 4x1: wave wv owns token rows [wv*32, wv*32+32) x all 128 N-cols
// (acc[2][8]); x is read exactly once per block (no wn-pair redundancy), the
// 16 KB per-kb W panel is L1-resident across the 4-way wave reuse, and softmax
// runs on all 4 waves. LDS (34816 B) only holds the epilogue transpose buffers
// for Phase C; 2 barriers per m0 (vs 40/block before).
// __launch_bounds__(256,1): empirically arg2 caps VGPR at 512/(2*arg2); the
// ~150-reg body would spill under the old (256,2) 128-reg cap.
__global__ __launch_bounds__(256, 1)
void fused_main(const float* __restrict__ x,   const float* __restrict__ bfx,
                const float* __restrict__ bsp, const float* __restrict__ temp,
                const f16* __restrict__ WC,    float* __restrict__ Tg,
                float* __restrict__ normg) {
  __shared__ alignas(16) f16 sm_fxT[64 * LDT];   // fx^T [d64][tok128]
  __shared__ alignas(16) f16 sm_wT [64 * LDT];   // w^T  [s64][tok128]

  // XCD swizzle: all 8 heads of a chunk on one XCD
  const int j    = blockIdx.x;
  const int xcd  = j & 7, slot = j >> 3;
  const int chunk = xcd * 32 + (slot >> 3);
  const int h     = slot & 7;

  const int tid = threadIdx.x;
  const int wv = tid >> 6, lane = tid & 63, quad = lane >> 4, ln = lane & 15;
  const long tokBase = (long)chunk * CHUNK;
  const int b  = (int)(tokBase >> 16);
  const int bh = b * Hc + h;

  const float tc = fminf(fmaxf(temp[h], 0.5f), 5.0f);
  const float k2 = 1.44269504f / tc;

  float bv[8];
  #pragma unroll
  for (int nt = 0; nt < 4; ++nt) bv[nt]     = bfx[h*64 + nt*16 + ln];
  #pragma unroll
  for (int nt = 0; nt < 4; ++nt) bv[4 + nt] = bsp[h*64 + nt*16 + ln];

  f32x4 Tacc[2][2];
  #pragma unroll
  for (int i = 0; i < 2; ++i) { Tacc[i][0] = splat4(0.f); Tacc[i][1] = splat4(0.f); }
  float nacc[4] = {0.f, 0.f, 0.f, 0.f};
  const int ci = wv >> 1, cj = wv & 1;

  const f16* WCh = WC + (size_t)h * 128 * 256;
  // per-lane base pointers (quad folded in)
  const float* xrow  = x + (tokBase + wv*32 + ln) * (long)Cc + quad*8;
  const f16*   wrowq = WCh + ln*256 + quad*8;

  for (int m0 = 0; m0 < 4; ++m0) {
    // ---------- Phase A: [fx | sp] = x_rows(32x256) @ WC_h(256x128), no LDS ----------
    f32x4 acc[2][8];
    #pragma unroll
    for (int mt = 0; mt < 2; ++mt)
      #pragma unroll
      for (int nt = 0; nt < 8; ++nt) acc[mt][nt] = splat4(bv[nt]);

    #pragma unroll
    for (int kb = 0; kb < 4; ++kb) {
      #pragma unroll
      for (int ks = 0; ks < 2; ++ks) {
        const int ko = kb*64 + ks*32;
        f16x8 af0, af1;
        {
          const float* p = xrow + ko;
          af0 = pack8(*(const float4*)p, *(const float4*)(p + 4));
          p += 16 * Cc;
          af1 = pack8(*(const float4*)p, *(const float4*)(p + 4));
        }
        f16x8 bf[8];
        #pragma unroll
        for (int nt = 0; nt < 8; ++nt)
          bf[nt] = *(const f16x8*)(wrowq + nt*(16*256) + ko);
        #pragma unroll
        for (int nt = 0; nt < 8; ++nt) {
          acc[0][nt] = MFMA(af0, bf[nt], acc[0][nt]);
          acc[1][nt] = MFMA(af1, bf[nt], acc[1][nt]);
        }
      }
    }

    __syncthreads();                       // prev Phase-C LDS reads done before overwrite

    // ---------- epilogue: transpose fx, softmax sp, into LDS ----------
    #pragma unroll
    for (int mt = 0; mt < 2; ++mt) {
      #pragma unroll
      for (int nt = 0; nt < 4; ++nt) {
        f32x4 a = acc[mt][nt];
        f16x4 v = { (f16)a[0], (f16)a[1], (f16)a[2], (f16)a[3] };
        *(f16x4*)&sm_fxT[(nt*16 + ln)*LDT + wv*32 + mt*16 + quad*4] = v;
      }
      float e[4][4];
      #pragma unroll
      for (int nt = 0; nt < 4; ++nt)
        #pragma unroll
        for (int rg = 0; rg < 4; ++rg)
          e[nt][rg] = exp2f(acc[mt][4 + nt][rg] * k2);   // no max-sub: logits bounded
      #pragma unroll
      for (int rg = 0; rg < 4; ++rg) {
        float rs = e[0][rg] + e[1][rg] + e[2][rg] + e[3][rg];
        #pragma unroll
        for (int dd = 1; dd < 16; dd <<= 1) rs += __shfl_xor(rs, dd, 64);
        float inv = 1.0f / rs;
        #pragma unroll
        for (int nt = 0; nt < 4; ++nt) {
          e[nt][rg] *= inv;
          nacc[nt] += e[nt][rg];
        }
      }
      #pragma unroll
      for (int nt = 0; nt < 4; ++nt) {
        f16x4 v = { (f16)e[nt][0], (f16)e[nt][1], (f16)e[nt][2], (f16)e[nt][3] };
        *(f16x4*)&sm_wT[(nt*16 + ln)*LDT + wv*32 + mt*16 + quad*4] = v;
      }
    }
    __syncthreads();                       // epilogue writes visible to all waves

    // ---------- Phase C: T[s][d] += w^T @ fx, K=128 ----------
    #pragma unroll
    for (int ks = 0; ks < 4; ++ks) {
      f16x8 a0 = *(const f16x8*)&sm_wT [(ci*32 +      ln)*LDT + ks*32 + quad*8];
      f16x8 a1 = *(const f16x8*)&sm_wT [(ci*32 + 16 + ln)*LDT + ks*32 + quad*8];
      f16x8 b0 = *(const f16x8*)&sm_fxT[(cj*32 +      ln)*LDT + ks*32 + quad*8];
      f16x8 b1 = *(const f16x8*)&sm_fxT[(cj*32 + 16 + ln)*LDT + ks*32 + quad*8];
      Tacc[0][0] = MFMA(a0, b0, Tacc[0][0]);
      Tacc[0][1] = MFMA(a0, b1, Tacc[0][1]);
      Tacc[1][0] = MFMA(a1, b0, Tacc[1][0]);
      Tacc[1][1] = MFMA(a1, b1, Tacc[1][1]);
    }
    // next m0's pre-epilogue barrier orders these reads vs transpose rewrites

    xrow += 128 * Cc;
  }

  // ---------- flush ----------
  float* Tb = Tg + bh * 4096;
  #pragma unroll
  for (int mt2 = 0; mt2 < 2; ++mt2)
    #pragma unroll
    for (int nt2 = 0; nt2 < 2; ++nt2)
      #pragma unroll
      for (int rg = 0; rg < 4; ++rg) {
        int s = ci*32 + mt2*16 + quad*4 + rg;
        int d = cj*32 + nt2*16 + ln;
        atomicAdd(&Tb[s*64 + d], Tacc[mt2][nt2][rg]);
      }
  #pragma unroll
  for (int nt = 0; nt < 4; ++nt) {
    float v = nacc[nt];
    v += __shfl_xor(v, 16, 64);
    v += __shfl_xor(v, 32, 64);
    if (lane < 16) atomicAdd(&normg[bh*64 + nt*16 + ln], v);
  }
}

__global__ void finalize(const float* __restrict__ Tg, const float* __restrict__ normg,
                         float* __restrict__ out) {
  int i = blockIdx.x * 256 + threadIdx.x;
  out[i] = Tg[i] / (normg[i >> 6] + 0.01f);
}

extern "C" void kernel_launch(void* const* d_in, const int* in_sizes, int n_in,
                              void* d_out, int out_size, void* d_ws, size_t ws_size,
                              hipStream_t stream) {
  const float* x    = (const float*)d_in[0];
  const float* Wx   = (const float*)d_in[1];
  const float* bx   = (const float*)d_in[2];
  const float* Wfx  = (const float*)d_in[3];
  const float* bfx  = (const float*)d_in[4];
  const float* Wsl  = (const float*)d_in[5];
  const float* bsl  = (const float*)d_in[6];
  const float* temp = (const float*)d_in[7];
  float* out = (float*)d_out;

  float* Tg    = (float*)d_ws;
  float* normg = Tg + 16 * 4096;
  f16*   WC    = (f16*)((char*)d_ws + 266240);
  float* bsp   = (float*)((char*)d_ws + 790528);

  hipMemsetAsync(d_ws, 0, 266240, stream);       // zero Tg + normg
  prep_a    <<<97, 256, 0, stream>>>(Wx, Wfx, Wsl, bx, bsl, WC, bsp);
  fused_main<<<2048, 256, 0, stream>>>(x, bfx, bsp, temp, WC, Tg, normg);
  finalize  <<<256, 256, 0, stream>>>(Tg, normg, out);
}

// Round 2
// 614.171 us; speedup vs baseline: 1.0928x; 1.0928x over previous
//
#include <hip/hip_runtime.h>

typedef _Float16 f16;
typedef __attribute__((ext_vector_type(8))) _Float16 f16x8;
typedef __attribute__((ext_vector_type(4))) _Float16 f16x4;
typedef __attribute__((ext_vector_type(4))) float    f32x4;

#define MFMA(a,b,c) __builtin_amdgcn_mfma_f32_16x16x32_f16(a,b,c,0,0,0)

// problem constants
constexpr int Bc = 2, Nc = 65536, Cc = 256, Hc = 8;
constexpr int CHUNK = 512;                 // tokens per block: 4 m0-tiles of 128
// Strides chosen so row-stride in 4B words ≡ 2 (mod 32): fragment-read bank
// starts spread over 16 banks (4 lanes/start, uniform 8 word-accesses/bank =
// the b128 minimum). Old LDX=72/LDT=136 were ≡ 4 (mod 32): 8 lanes/start.
constexpr int LDX = 68;                    // staging stride (f16), 34 words
constexpr int LDT = 132;                   // fxT/wT transpose stride (f16), 66 words

// ---- workspace layout (bytes) ----
// 0      : Tg    float[16*4096] (262144)
// 262144 : normg float[16*64]   (4096)
// 266240 : WC    f16[8*128*256] (524288)  [h][n][k]; n 0..63 = Wfx cols, 64..127 = Wxs = Wx_h@Ws
// 790528 : bsp   float[8*64]    (2048)    folded slice bias: bx_h@Ws + bsl

__device__ __forceinline__ f32x4 splat4(float v) { f32x4 r; r.x=v; r.y=v; r.z=v; r.w=v; return r; }
__device__ __forceinline__ f16x8 pack8(float4 a, float4 b) {
  f16x8 r = { (f16)a.x,(f16)a.y,(f16)a.z,(f16)a.w,(f16)b.x,(f16)b.y,(f16)b.z,(f16)b.w };
  return r;
}

// prep: 97 blocks. (unchanged)
__global__ void prep_a(const float* __restrict__ Wx, const float* __restrict__ Wfx,
                       const float* __restrict__ Wsl, const float* __restrict__ bx,
                       const float* __restrict__ bsl, f16* __restrict__ WC,
                       float* __restrict__ bsp) {
  __shared__ float tile[64][72];
  const int b = blockIdx.x, t = threadIdx.x;
  if (b < 32) {                            // transpose Wfx tile (k0..+64) x (c0..+64)
    const int k0 = (b & 3) * 64, c0 = (b >> 2) * 64;
    const int r = t >> 4, c4 = (t & 15) * 4;
    #pragma unroll
    for (int i = 0; i < 4; ++i) {
      float4 v = *(const float4*)&Wfx[(size_t)(k0 + r + i*16)*512 + c0 + c4];
      tile[r + i*16][c4] = v.x; tile[r + i*16][c4+1] = v.y;
      tile[r + i*16][c4+2] = v.z; tile[r + i*16][c4+3] = v.w;
    }
    __syncthreads();
    const int cl = t >> 2, kq = t & 3;
    const int col = c0 + cl, h = col >> 6, n = col & 63;
    f16 tmp[16];
    #pragma unroll
    for (int j = 0; j < 16; ++j) tmp[j] = (f16)tile[kq*16 + j][cl];
    f16* dst = WC + (size_t)(h*128 + n)*256 + k0 + kq*16;
    *(f16x8*)dst       = *(f16x8*)&tmp[0];
    *(f16x8*)(dst + 8) = *(f16x8*)&tmp[8];
  } else if (b < 96) {                     // Wxs rows
    const int bb = b - 32;
    const int h = bb >> 3, k0 = (bb & 7) * 32;
    const int k = t & 31, sq = t >> 5;     // 8 s-values per thread
    float accs[8];
    #pragma unroll
    for (int j = 0; j < 8; ++j) accs[j] = 0.f;
    for (int d = 0; d < 64; ++d) {
      float a = Wx[(size_t)(k0 + k)*512 + h*64 + d];
      #pragma unroll
      for (int j = 0; j < 8; ++j) accs[j] += a * Wsl[d*64 + sq*8 + j];
    }
    #pragma unroll
    for (int j = 0; j < 8; ++j)
      WC[(size_t)(h*128 + 64 + sq*8 + j)*256 + k0 + k] = (f16)accs[j];
  } else {                                 // bsp[h][s]
    for (int u = t; u < 512; u += 256) {
      int h = u >> 6, s = u & 63;
      float a = bsl[s];
      for (int d = 0; d < 64; ++d) a += bx[h*64 + d] * Wsl[d*64 + s];
      bsp[h*64 + s] = a;
    }
  }
}

// Round-0 structure (coalesced global loads + register-staged LDS, 2x2 wave
// grid) with the K-loop flattened to 16 tile-steps and TRUE double-buffered
// staging: step t MFMAs from buf[t&1], writes tile t+1 into buf[t^1], issues
// global loads for tile t+2. ONE barrier per step (23/block vs 40), and the
// ds_writes + global loads overlap MFMA instead of being barrier-serialized.
// Transpose buffers alias buf1: at epilogue time (steps 3,7,11,15 — all odd)
// buf1's staging data was just consumed; the next buf1 staging write (step
// t+1) sits behind that step's opening barrier, which also orders Phase-C
// reads. LDS 69632 B -> 2 blocks/CU.
__global__ __launch_bounds__(256, 2)
void fused_main(const float* __restrict__ x,   const float* __restrict__ bfx,
                const float* __restrict__ bsp, const float* __restrict__ temp,
                const f16* __restrict__ WC,    float* __restrict__ Tg,
                float* __restrict__ normg) {
  __shared__ alignas(16) char smem[4 * 128 * LDX * 2];   // 69632 B
  f16* X0 = (f16*)smem;                    // staging x, even tiles
  f16* W0 = X0 + 128 * LDX;                // staging w, even tiles
  f16* X1 = W0 + 128 * LDX;                // staging x, odd tiles | alias fx^T [64][LDT]
  f16* W1 = X1 + 128 * LDX;                // staging w, odd tiles | alias w^T  [64][LDT]
  f16* sm_fxT = X1;                        // 64*132*2 = 16896 B <= 17408 B region
  f16* sm_wT  = W1;

  // XCD swizzle: all 8 heads of a chunk on one XCD
  const int j    = blockIdx.x;
  const int xcd  = j & 7, slot = j >> 3;
  const int chunk = xcd * 32 + (slot >> 3);
  const int h     = slot & 7;

  const int tid = threadIdx.x;
  const int wv = tid >> 6, lane = tid & 63, quad = lane >> 4, ln = lane & 15;
  const int wm = wv >> 1, wn = wv & 1;
  const long tokBase = (long)chunk * CHUNK;
  const int b  = (int)(tokBase >> 16);
  const int bh = b * Hc + h;

  const float tc = fminf(fmaxf(temp[h], 0.5f), 5.0f);
  const float k2 = 1.44269504f / tc;

  float bv[4];
  {
    const float* bb = (wn == 0) ? (bfx + h*64) : (bsp + h*64);
    #pragma unroll
    for (int nt = 0; nt < 4; ++nt) bv[nt] = bb[nt*16 + ln];
  }

  f32x4 Tacc[2][2];
  #pragma unroll
  for (int i = 0; i < 2; ++i) { Tacc[i][0] = splat4(0.f); Tacc[i][1] = splat4(0.f); }
  float nacc[4] = {0.f, 0.f, 0.f, 0.f};
  const int ci = wv >> 1, cj = wv & 1;

  const f16* WCh = WC + (size_t)h * 128 * 256;

  const int r0 = tid >> 2, seg = tid & 3;
  const int wrow = tid >> 1, whalf = tid & 1;

  float4 xr[8]; f16x8 wr[4];
  auto loadx = [&](int m0, int kb) {
    const float* p = x + (tokBase + (long)m0*128 + r0)*Cc + kb*64 + seg*16;
    xr[0] = *(const float4*)p;        xr[1] = *(const float4*)(p + 4);
    xr[2] = *(const float4*)(p + 8);  xr[3] = *(const float4*)(p + 12);
    p += 64 * Cc;
    xr[4] = *(const float4*)p;        xr[5] = *(const float4*)(p + 4);
    xr[6] = *(const float4*)(p + 8);  xr[7] = *(const float4*)(p + 12);
  };
  auto loadw = [&](int kb) {
    const f16* p = WCh + wrow*256 + kb*64 + whalf*32;
    wr[0] = *(const f16x8*)p;         wr[1] = *(const f16x8*)(p + 8);
    wr[2] = *(const f16x8*)(p + 16);  wr[3] = *(const f16x8*)(p + 24);
  };
  auto store_tile = [&](int p) {           // write regs (one 128x64 tile pair) to buf p
    f16* sx = p ? X1 : X0;
    f16* sw = p ? W1 : W0;
    *(f16x8*)&sx[r0*LDX + seg*16]          = pack8(xr[0], xr[1]);
    *(f16x8*)&sx[r0*LDX + seg*16 + 8]      = pack8(xr[2], xr[3]);
    *(f16x8*)&sx[(r0+64)*LDX + seg*16]     = pack8(xr[4], xr[5]);
    *(f16x8*)&sx[(r0+64)*LDX + seg*16 + 8] = pack8(xr[6], xr[7]);
    *(f16x8*)&sw[wrow*LDX + whalf*32]      = wr[0];
    *(f16x8*)&sw[wrow*LDX + whalf*32 +  8] = wr[1];
    *(f16x8*)&sw[wrow*LDX + whalf*32 + 16] = wr[2];
    *(f16x8*)&sw[wrow*LDX + whalf*32 + 24] = wr[3];
  };

  // prologue: tile0 staged, tile1 in regs
  loadx(0, 0); loadw(0);
  store_tile(0);
  loadx(0, 1); loadw(1);
  __syncthreads();

  for (int m0 = 0; m0 < 4; ++m0) {
    f32x4 acc[4][4];
    #pragma unroll
    for (int mt = 0; mt < 4; ++mt)
      #pragma unroll
      for (int nt = 0; nt < 4; ++nt) acc[mt][nt] = splat4(bv[nt]);

    #pragma unroll
    for (int kb = 0; kb < 4; ++kb) {
      const int t = m0*4 + kb;
      if (t > 0) __syncthreads();          // buf[t&1] staged; buf[t^1] reads (t-1) done
      const f16* sx = (t & 1) ? X1 : X0;
      const f16* sw = (t & 1) ? W1 : W0;

      // ks=0 fragment reads issued FIRST (DS queue order lets MFMA start
      // before the staging writes below drain)
      f16x8 af[4], bf[4];
      #pragma unroll
      for (int mt = 0; mt < 4; ++mt)
        af[mt] = *(const f16x8*)&sx[(wm*64 + mt*16 + ln)*LDX + quad*8];
      #pragma unroll
      for (int nt = 0; nt < 4; ++nt)
        bf[nt] = *(const f16x8*)&sw[(wn*64 + nt*16 + ln)*LDX + quad*8];

      if (t + 1 < 16) store_tile((t + 1) & 1);            // tile t+1 -> other buf
      if (t + 2 < 16) { loadx((t + 2) >> 2, (t + 2) & 3); // tile t+2 -> regs
                        loadw((t + 2) & 3); }

      #pragma unroll
      for (int mt = 0; mt < 4; ++mt)
        #pragma unroll
        for (int nt = 0; nt < 4; ++nt)
          acc[mt][nt] = MFMA(af[mt], bf[nt], acc[mt][nt]);

      // ks=1
      #pragma unroll
      for (int mt = 0; mt < 4; ++mt)
        af[mt] = *(const f16x8*)&sx[(wm*64 + mt*16 + ln)*LDX + 32 + quad*8];
      #pragma unroll
      for (int nt = 0; nt < 4; ++nt)
        bf[nt] = *(const f16x8*)&sw[(wn*64 + nt*16 + ln)*LDX + 32 + quad*8];
      #pragma unroll
      for (int mt = 0; mt < 4; ++mt)
        #pragma unroll
        for (int nt = 0; nt < 4; ++nt)
          acc[mt][nt] = MFMA(af[mt], bf[nt], acc[mt][nt]);
    }
    __syncthreads();                       // all waves' reads of buf1 done (alias rewrite ok)

    // ---------- epilogue into aliased buf1 ----------
    if (wn == 0) {
      #pragma unroll
      for (int mt = 0; mt < 4; ++mt)
        #pragma unroll
        for (int nt = 0; nt < 4; ++nt) {
          f16x4 v = { (f16)acc[mt][nt][0], (f16)acc[mt][nt][1],
                      (f16)acc[mt][nt][2], (f16)acc[mt][nt][3] };
          *(f16x4*)&sm_fxT[(nt*16 + ln)*LDT + wm*64 + mt*16 + quad*4] = v;
        }
    } else {
      #pragma unroll
      for (int mt = 0; mt < 4; ++mt) {
        float e[4][4], wout[4][4];
        #pragma unroll
        for (int nt = 0; nt < 4; ++nt)
          #pragma unroll
          for (int rg = 0; rg < 4; ++rg)
            e[nt][rg] = exp2f(acc[mt][nt][rg] * k2);   // no max-sub: logits bounded
        #pragma unroll
        for (int rg = 0; rg < 4; ++rg) {
          float rs = e[0][rg] + e[1][rg] + e[2][rg] + e[3][rg];
          #pragma unroll
          for (int dd = 1; dd < 16; dd <<= 1) rs += __shfl_xor(rs, dd, 64);
          float inv = 1.0f / rs;
          #pragma unroll
          for (int nt = 0; nt < 4; ++nt) {
            wout[nt][rg] = e[nt][rg] * inv;
            nacc[nt] += wout[nt][rg];
          }
        }
        #pragma unroll
        for (int nt = 0; nt < 4; ++nt) {
          f16x4 v = { (f16)wout[nt][0], (f16)wout[nt][1],
                      (f16)wout[nt][2], (f16)wout[nt][3] };
          *(f16x4*)&sm_wT[(nt*16 + ln)*LDT + wm*64 + mt*16 + quad*4] = v;
        }
      }
    }
    __syncthreads();                       // epilogue writes visible

    // ---------- Phase C: T[s][d] += w^T @ fx, K=128 ----------
    #pragma unroll
    for (int ks = 0; ks < 4; ++ks) {
      f16x8 a0 = *(const f16x8*)&sm_wT [(ci*32 +      ln)*LDT + ks*32 + quad*8];
      f16x8 a1 = *(const f16x8*)&sm_wT [(ci*32 + 16 + ln)*LDT + ks*32 + quad*8];
      f16x8 b0 = *(const f16x8*)&sm_fxT[(cj*32 +      ln)*LDT + ks*32 + quad*8];
      f16x8 b1 = *(const f16x8*)&sm_fxT[(cj*32 + 16 + ln)*LDT + ks*32 + quad*8];
      Tacc[0][0] = MFMA(a0, b0, Tacc[0][0]);
      Tacc[0][1] = MFMA(a0, b1, Tacc[0][1]);
      Tacc[1][0] = MFMA(a1, b0, Tacc[1][0]);
      Tacc[1][1] = MFMA(a1, b1, Tacc[1][1]);
    }
    // next step's opening barrier orders these reads vs the buf1 staging rewrite
  }

  // ---------- flush ----------
  float* Tb = Tg + bh * 4096;
  #pragma unroll
  for (int mt2 = 0; mt2 < 2; ++mt2)
    #pragma unroll
    for (int nt2 = 0; nt2 < 2; ++nt2)
      #pragma unroll
      for (int rg = 0; rg < 4; ++rg) {
        int s = ci*32 + mt2*16 + quad*4 + rg;
        int d = cj*32 + nt2*16 + ln;
        atomicAdd(&Tb[s*64 + d], Tacc[mt2][nt2][rg]);
      }
  if (wn == 1) {
    #pragma unroll
    for (int nt = 0; nt < 4; ++nt) {
      float v = nacc[nt];
      v += __shfl_xor(v, 16, 64);
      v += __shfl_xor(v, 32, 64);
      if (lane < 16) atomicAdd(&normg[bh*64 + nt*16 + ln], v);
    }
  }
}

__global__ void finalize(const float* __restrict__ Tg, const float* __restrict__ normg,
                         float* __restrict__ out) {
  int i = blockIdx.x * 256 + threadIdx.x;
  out[i] = Tg[i] / (normg[i >> 6] + 0.01f);
}

extern "C" void kernel_launch(void* const* d_in, const int* in_sizes, int n_in,
                              void* d_out, int out_size, void* d_ws, size_t ws_size,
                              hipStream_t stream) {
  const float* x    = (const float*)d_in[0];
  const float* Wx   = (const float*)d_in[1];
  const float* bx   = (const float*)d_in[2];
  const float* Wfx  = (const float*)d_in[3];
  const float* bfx  = (const float*)d_in[4];
  const float* Wsl  = (const float*)d_in[5];
  const float* bsl  = (const float*)d_in[6];
  const float* temp = (const float*)d_in[7];
  float* out = (float*)d_out;

  float* Tg    = (float*)d_ws;
  float* normg = Tg + 16 * 4096;
  f16*   WC    = (f16*)((char*)d_ws + 266240);
  float* bsp   = (float*)((char*)d_ws + 790528);

  hipMemsetAsync(d_ws, 0, 266240, stream);       // zero Tg + normg
  prep_a    <<<97, 256, 0, stream>>>(Wx, Wfx, Wsl, bx, bsl, WC, bsp);
  fused_main<<<2048, 256, 0, stream>>>(x, bfx, bsp, temp, WC, Tg, normg);
  finalize  <<<256, 256, 0, stream>>>(Tg, normg, out);
}

// Round 3
// 611.204 us; speedup vs baseline: 1.0981x; 1.0049x over previous
//
#include <hip/hip_runtime.h>

typedef _Float16 f16;
typedef __attribute__((ext_vector_type(8))) _Float16 f16x8;
typedef __attribute__((ext_vector_type(4))) _Float16 f16x4;
typedef __attribute__((ext_vector_type(4))) float    f32x4;

#define MFMA(a,b,c) __builtin_amdgcn_mfma_f32_16x16x32_f16(a,b,c,0,0,0)

// problem constants
constexpr int Bc = 2, Nc = 65536, Cc = 256, Hc = 8;
constexpr int CHUNK = 512;                 // tokens per block: 4 m0-tiles of 128
// Strides: row stride in 4B words ≡ 2 (mod 32) → fragment b128 reads/writes
// are uniform 8 word-accesses/bank (the minimum). Round-2 measured
// SQ_LDS_BANK_CONFLICT == 0 with these; old LDX=72/LDT=136 (≡4 mod 32)
// measured 1.26e7 conflict cycles.
constexpr int LDX = 68;                    // staging stride (f16), 34 words
constexpr int LDT = 132;                   // fxT/wT stride (f16), 66 words

// ---- workspace layout (bytes) ----
// 0      : Tg    float[16*4096] (262144)
// 262144 : normg float[16*64]   (4096)
// 266240 : WC    f16[8*128*256] (524288)  [h][n][k]; n 0..63 = Wfx cols, 64..127 = Wxs = Wx_h@Ws
// 790528 : bsp   float[8*64]    (2048)    folded slice bias: bx_h@Ws + bsl

__device__ __forceinline__ f32x4 splat4(float v) { f32x4 r; r.x=v; r.y=v; r.z=v; r.w=v; return r; }
__device__ __forceinline__ f16x8 pack8(float4 a, float4 b) {
  f16x8 r = { (f16)a.x,(f16)a.y,(f16)a.z,(f16)a.w,(f16)b.x,(f16)b.y,(f16)b.z,(f16)b.w };
  return r;
}

// prep: 162 blocks. b<32: Wfx transpose; 32<=b<96: Wxs; b==96: bsp;
// 97<=b<162: zero Tg+normg (replaces the hipMemsetAsync dispatch — 65 blocks
// x 256 threads x float4 = 266240 B exactly).
__global__ void prep_a(const float* __restrict__ Wx, const float* __restrict__ Wfx,
                       const float* __restrict__ Wsl, const float* __restrict__ bx,
                       const float* __restrict__ bsl, f16* __restrict__ WC,
                       float* __restrict__ bsp, float* __restrict__ Tz) {
  __shared__ float tile[64][72];
  const int b = blockIdx.x, t = threadIdx.x;
  if (b < 32) {                            // transpose Wfx tile (k0..+64) x (c0..+64)
    const int k0 = (b & 3) * 64, c0 = (b >> 2) * 64;
    const int r = t >> 4, c4 = (t & 15) * 4;
    #pragma unroll
    for (int i = 0; i < 4; ++i) {
      float4 v = *(const float4*)&Wfx[(size_t)(k0 + r + i*16)*512 + c0 + c4];
      tile[r + i*16][c4] = v.x; tile[r + i*16][c4+1] = v.y;
      tile[r + i*16][c4+2] = v.z; tile[r + i*16][c4+3] = v.w;
    }
    __syncthreads();
    const int cl = t >> 2, kq = t & 3;
    const int col = c0 + cl, h = col >> 6, n = col & 63;
    f16 tmp[16];
    #pragma unroll
    for (int j = 0; j < 16; ++j) tmp[j] = (f16)tile[kq*16 + j][cl];
    f16* dst = WC + (size_t)(h*128 + n)*256 + k0 + kq*16;
    *(f16x8*)dst       = *(f16x8*)&tmp[0];
    *(f16x8*)(dst + 8) = *(f16x8*)&tmp[8];
  } else if (b < 96) {                     // Wxs rows
    const int bb = b - 32;
    const int h = bb >> 3, k0 = (bb & 7) * 32;
    const int k = t & 31, sq = t >> 5;     // 8 s-values per thread
    float accs[8];
    #pragma unroll
    for (int j = 0; j < 8; ++j) accs[j] = 0.f;
    for (int d = 0; d < 64; ++d) {
      float a = Wx[(size_t)(k0 + k)*512 + h*64 + d];
      #pragma unroll
      for (int j = 0; j < 8; ++j) accs[j] += a * Wsl[d*64 + sq*8 + j];
    }
    #pragma unroll
    for (int j = 0; j < 8; ++j)
      WC[(size_t)(h*128 + 64 + sq*8 + j)*256 + k0 + k] = (f16)accs[j];
  } else if (b == 96) {                    // bsp[h][s]
    for (int u = t; u < 512; u += 256) {
      int h = u >> 6, s = u & 63;
      float a = bsl[s];
      for (int d = 0; d < 64; ++d) a += bx[h*64 + d] * Wsl[d*64 + s];
      bsp[h*64 + s] = a;
    }
  } else {                                 // zero Tg + normg
    float4 z; z.x = z.y = z.z = z.w = 0.f;
    ((float4*)Tz)[(b - 97) * 256 + t] = z;
  }
}

// Round-0 structure restored verbatim (201 µs, 112 VGPR, no spill): coalesced
// register-staged LDS, single-buffered, 2x2 wave grid, 2 barriers/kb. Only the
// LDS strides changed (conflict-free per round-2 measurement).
// (256,2): empirically the arg-2 cap is VGPR<=512/(2*arg2); (256,4) forced 64
// VGPR and spilled. LDS 34816 B allows 4 blocks/CU.
__global__ __launch_bounds__(256, 2)
void fused_main(const float* __restrict__ x,   const float* __restrict__ bfx,
                const float* __restrict__ bsp, const float* __restrict__ temp,
                const f16* __restrict__ WC,    float* __restrict__ Tg,
                float* __restrict__ normg) {
  // two 17408-B buffers; staging [128][LDX] aliased with transposed [64][LDT]
  __shared__ alignas(16) char smem[2 * 128 * LDX * 2];   // 34816 B
  f16* sm_x   = (f16*)smem;                // x staging    | alias: fx^T [d64][tok128]
  f16* sm_w   = (f16*)(smem + 128*LDX*2);  // W staging    | alias: w^T  [s64][tok128]
  f16* sm_fxT = sm_x;                      // 64*132*2 = 16896 B <= 17408 B region
  f16* sm_wT  = sm_w;

  // XCD swizzle: all 8 heads of a chunk on one XCD
  const int j    = blockIdx.x;
  const int xcd  = j & 7, slot = j >> 3;
  const int chunk = xcd * 32 + (slot >> 3);
  const int h     = slot & 7;

  const int tid = threadIdx.x;
  const int wv = tid >> 6, lane = tid & 63, quad = lane >> 4, ln = lane & 15;
  const int wm = wv >> 1, wn = wv & 1;
  const long tokBase = (long)chunk * CHUNK;
  const int b  = (int)(tokBase >> 16);
  const int bh = b * Hc + h;

  const float tc = fminf(fmaxf(temp[h], 0.5f), 5.0f);
  const float k2 = 1.44269504f / tc;

  float bv[4];
  {
    const float* bb = (wn == 0) ? (bfx + h*64) : (bsp + h*64);
    #pragma unroll
    for (int nt = 0; nt < 4; ++nt) bv[nt] = bb[nt*16 + ln];
  }

  f32x4 Tacc[2][2];
  #pragma unroll
  for (int i = 0; i < 2; ++i) { Tacc[i][0] = splat4(0.f); Tacc[i][1] = splat4(0.f); }
  float nacc[4] = {0.f, 0.f, 0.f, 0.f};
  const int ci = wv >> 1, cj = wv & 1;

  const f16* WCh = WC + (size_t)h * 128 * 256;

  const int r0 = tid >> 2, seg = tid & 3;
  const int wrow = tid >> 1, whalf = tid & 1;

  float4 xr[8]; f16x8 wr[4];
  auto loadx = [&](int m0, int kb) {
    const float* p = x + (tokBase + (long)m0*128 + r0)*Cc + kb*64 + seg*16;
    xr[0] = *(const float4*)p;        xr[1] = *(const float4*)(p + 4);
    xr[2] = *(const float4*)(p + 8);  xr[3] = *(const float4*)(p + 12);
    p += 64 * Cc;
    xr[4] = *(const float4*)p;        xr[5] = *(const float4*)(p + 4);
    xr[6] = *(const float4*)(p + 8);  xr[7] = *(const float4*)(p + 12);
  };
  auto loadw = [&](int kb) {
    const f16* p = WCh + wrow*256 + kb*64 + whalf*32;
    wr[0] = *(const f16x8*)p;         wr[1] = *(const f16x8*)(p + 8);
    wr[2] = *(const f16x8*)(p + 16);  wr[3] = *(const f16x8*)(p + 24);
  };

  loadx(0, 0); loadw(0);

  for (int m0 = 0; m0 < 4; ++m0) {
    // ---------- Phase A: [fx | sp] = x_tile(128x256) @ WC_h(256x128) ----------
    f32x4 acc[4][4];
    #pragma unroll
    for (int mt = 0; mt < 4; ++mt)
      #pragma unroll
      for (int nt = 0; nt < 4; ++nt) acc[mt][nt] = splat4(bv[nt]);

    for (int kb = 0; kb < 4; ++kb) {
      __syncthreads();                     // prev phase-C / MFMA reads done before overwrite
      *(f16x8*)&sm_x[r0*LDX + seg*16]          = pack8(xr[0], xr[1]);
      *(f16x8*)&sm_x[r0*LDX + seg*16 + 8]      = pack8(xr[2], xr[3]);
      *(f16x8*)&sm_x[(r0+64)*LDX + seg*16]     = pack8(xr[4], xr[5]);
      *(f16x8*)&sm_x[(r0+64)*LDX + seg*16 + 8] = pack8(xr[6], xr[7]);
      *(f16x8*)&sm_w[wrow*LDX + whalf*32]      = wr[0];
      *(f16x8*)&sm_w[wrow*LDX + whalf*32 +  8] = wr[1];
      *(f16x8*)&sm_w[wrow*LDX + whalf*32 + 16] = wr[2];
      *(f16x8*)&sm_w[wrow*LDX + whalf*32 + 24] = wr[3];
      { int nkb = kb + 1, nm0 = m0;
        if (nkb == 4) { nkb = 0; ++nm0; }
        if (nm0 < 4) { loadx(nm0, nkb); loadw(nkb); } }
      __syncthreads();
      #pragma unroll
      for (int ks = 0; ks < 2; ++ks) {
        f16x8 af[4], bf[4];
        #pragma unroll
        for (int mt = 0; mt < 4; ++mt)
          af[mt] = *(const f16x8*)&sm_x[(wm*64 + mt*16 + ln)*LDX + ks*32 + quad*8];
        #pragma unroll
        for (int nt = 0; nt < 4; ++nt)
          bf[nt] = *(const f16x8*)&sm_w[(wn*64 + nt*16 + ln)*LDX + ks*32 + quad*8];
        #pragma unroll
        for (int mt = 0; mt < 4; ++mt)
          #pragma unroll
          for (int nt = 0; nt < 4; ++nt)
            acc[mt][nt] = MFMA(af[mt], bf[nt], acc[mt][nt]);
      }
    }
    __syncthreads();                       // all phase-A LDS reads done before alias rewrite

    // ---------- epilogue into aliased buffers ----------
    if (wn == 0) {
      #pragma unroll
      for (int mt = 0; mt < 4; ++mt)
        #pragma unroll
        for (int nt = 0; nt < 4; ++nt) {
          f16x4 v = { (f16)acc[mt][nt][0], (f16)acc[mt][nt][1],
                      (f16)acc[mt][nt][2], (f16)acc[mt][nt][3] };
          *(f16x4*)&sm_fxT[(nt*16 + ln)*LDT + wm*64 + mt*16 + quad*4] = v;
        }
    } else {
      #pragma unroll
      for (int mt = 0; mt < 4; ++mt) {
        float e[4][4], wout[4][4];
        #pragma unroll
        for (int nt = 0; nt < 4; ++nt)
          #pragma unroll
          for (int rg = 0; rg < 4; ++rg)
            e[nt][rg] = exp2f(acc[mt][nt][rg] * k2);   // no max-sub: logits bounded
        #pragma unroll
        for (int rg = 0; rg < 4; ++rg) {
          float rs = e[0][rg] + e[1][rg] + e[2][rg] + e[3][rg];
          #pragma unroll
          for (int dd = 1; dd < 16; dd <<= 1) rs += __shfl_xor(rs, dd, 64);
          float inv = 1.0f / rs;
          #pragma unroll
          for (int nt = 0; nt < 4; ++nt) {
            wout[nt][rg] = e[nt][rg] * inv;
            nacc[nt] += wout[nt][rg];
          }
        }
        #pragma unroll
        for (int nt = 0; nt < 4; ++nt) {
          f16x4 v = { (f16)wout[nt][0], (f16)wout[nt][1],
                      (f16)wout[nt][2], (f16)wout[nt][3] };
          *(f16x4*)&sm_wT[(nt*16 + ln)*LDT + wm*64 + mt*16 + quad*4] = v;
        }
      }
    }
    __syncthreads();

    // ---------- Phase C: T[s][d] += w^T @ fx, K=128 ----------
    #pragma unroll
    for (int ks = 0; ks < 4; ++ks) {
      f16x8 a0 = *(const f16x8*)&sm_wT [(ci*32 +      ln)*LDT + ks*32 + quad*8];
      f16x8 a1 = *(const f16x8*)&sm_wT [(ci*32 + 16 + ln)*LDT + ks*32 + quad*8];
      f16x8 b0 = *(const f16x8*)&sm_fxT[(cj*32 +      ln)*LDT + ks*32 + quad*8];
      f16x8 b1 = *(const f16x8*)&sm_fxT[(cj*32 + 16 + ln)*LDT + ks*32 + quad*8];
      Tacc[0][0] = MFMA(a0, b0, Tacc[0][0]);
      Tacc[0][1] = MFMA(a0, b1, Tacc[0][1]);
      Tacc[1][0] = MFMA(a1, b0, Tacc[1][0]);
      Tacc[1][1] = MFMA(a1, b1, Tacc[1][1]);
    }
    // next m0's kb=0 barrier orders these reads vs staging rewrites
  }

  // ---------- flush ----------
  float* Tb = Tg + bh * 4096;
  #pragma unroll
  for (int mt2 = 0; mt2 < 2; ++mt2)
    #pragma unroll
    for (int nt2 = 0; nt2 < 2; ++nt2)
      #pragma unroll
      for (int rg = 0; rg < 4; ++rg) {
        int s = ci*32 + mt2*16 + quad*4 + rg;
        int d = cj*32 + nt2*16 + ln;
        atomicAdd(&Tb[s*64 + d], Tacc[mt2][nt2][rg]);
      }
  if (wn == 1) {
    #pragma unroll
    for (int nt = 0; nt < 4; ++nt) {
      float v = nacc[nt];
      v += __shfl_xor(v, 16, 64);
      v += __shfl_xor(v, 32, 64);
      if (lane < 16) atomicAdd(&normg[bh*64 + nt*16 + ln], v);
    }
  }
}

__global__ void finalize(const float* __restrict__ Tg, const float* __restrict__ normg,
                         float* __restrict__ out) {
  int i = blockIdx.x * 256 + threadIdx.x;
  out[i] = Tg[i] / (normg[i >> 6] + 0.01f);
}

extern "C" void kernel_launch(void* const* d_in, const int* in_sizes, int n_in,
                              void* d_out, int out_size, void* d_ws, size_t ws_size,
                              hipStream_t stream) {
  const float* x    = (const float*)d_in[0];
  const float* Wx   = (const float*)d_in[1];
  const float* bx   = (const float*)d_in[2];
  const float* Wfx  = (const float*)d_in[3];
  const float* bfx  = (const float*)d_in[4];
  const float* Wsl  = (const float*)d_in[5];
  const float* bsl  = (const float*)d_in[6];
  const float* temp = (const float*)d_in[7];
  float* out = (float*)d_out;

  float* Tg    = (float*)d_ws;
  float* normg = Tg + 16 * 4096;
  f16*   WC    = (f16*)((char*)d_ws + 266240);
  float* bsp   = (float*)((char*)d_ws + 790528);

  prep_a    <<<162, 256, 0, stream>>>(Wx, Wfx, Wsl, bx, bsl, WC, bsp, Tg);
  fused_main<<<2048, 256, 0, stream>>>(x, bfx, bsp, temp, WC, Tg, normg);
  finalize  <<<256, 256, 0, stream>>>(Tg, normg, out);
}

// Round 4
// 343.946 us; speedup vs baseline: 1.9514x; 1.7770x over previous
//
#include <hip/hip_runtime.h>

typedef _Float16 f16;
typedef __attribute__((ext_vector_type(8))) _Float16 f16x8;
typedef __attribute__((ext_vector_type(4))) _Float16 f16x4;
typedef __attribute__((ext_vector_type(4))) float    f32x4;

#define MFMA(a,b,c) __builtin_amdgcn_mfma_f32_16x16x32_f16(a,b,c,0,0,0)

// problem constants
constexpr int Bc = 2, Nc = 65536, Cc = 256, Hc = 8;
constexpr int CHUNK = 512;                 // tokens per block: 4 m0-tiles of 128
// STRIDES MUST KEEP 16B ALIGNMENT: rounds 2/3 used LDX=68/LDT=132 (136B/264B
// rows) -> odd rows put ds_*_b128 at 8 mod 16 -> fused_main 201->473 µs with
// IDENTICAL instruction counts and SQ_LDS_BANK_CONFLICT==0. The ~20µs of
// conflicts at LDX=72 is the cheap problem; misalignment is the expensive one.
constexpr int LDX = 72;                    // staging stride (f16), 144 B rows
constexpr int LDT = 136;                   // fxT/wT stride (f16), 272 B rows

// ---- workspace layout (bytes) ----
// 0      : Tg    float[16*4096] (262144)
// 262144 : normg float[16*64]   (4096)
// 266240 : WC    f16[8*128*256] (524288)  [h][n][k]; n 0..63 = Wfx cols, 64..127 = Wxs = Wx_h@Ws
// 790528 : bsp   float[8*64]    (2048)    folded slice bias: bx_h@Ws + bsl

__device__ __forceinline__ f32x4 splat4(float v) { f32x4 r; r.x=v; r.y=v; r.z=v; r.w=v; return r; }
__device__ __forceinline__ f16x8 pack8(float4 a, float4 b) {
  f16x8 r = { (f16)a.x,(f16)a.y,(f16)a.z,(f16)a.w,(f16)b.x,(f16)b.y,(f16)b.z,(f16)b.w };
  return r;
}

// Raw barrier: drain only LDS (lgkmcnt), NOT vmcnt — in-flight global loads
// survive across it. hipcc emits a full vmcnt(0) before __syncthreads(), which
// serialized every kb-step's next-tile loads in front of its MFMAs (the ~120µs
// stall at 201µs). "memory" clobber + sched_barrier(0) pin the LDS ops on the
// correct side (guide rule #18 class).
__device__ __forceinline__ void wave_bar() {
  asm volatile("s_waitcnt lgkmcnt(0)" ::: "memory");
  __builtin_amdgcn_s_barrier();
  __builtin_amdgcn_sched_barrier(0);
}

// prep: 162 blocks. b<32: Wfx transpose; 32<=b<96: Wxs; b==96: bsp;
// 97<=b<162: zero Tg+normg (65 blocks x 256 threads x float4 = 266240 B).
__global__ void prep_a(const float* __restrict__ Wx, const float* __restrict__ Wfx,
                       const float* __restrict__ Wsl, const float* __restrict__ bx,
                       const float* __restrict__ bsl, f16* __restrict__ WC,
                       float* __restrict__ bsp, float* __restrict__ Tz) {
  __shared__ float tile[64][72];
  const int b = blockIdx.x, t = threadIdx.x;
  if (b < 32) {                            // transpose Wfx tile (k0..+64) x (c0..+64)
    const int k0 = (b & 3) * 64, c0 = (b >> 2) * 64;
    const int r = t >> 4, c4 = (t & 15) * 4;
    #pragma unroll
    for (int i = 0; i < 4; ++i) {
      float4 v = *(const float4*)&Wfx[(size_t)(k0 + r + i*16)*512 + c0 + c4];
      tile[r + i*16][c4] = v.x; tile[r + i*16][c4+1] = v.y;
      tile[r + i*16][c4+2] = v.z; tile[r + i*16][c4+3] = v.w;
    }
    __syncthreads();
    const int cl = t >> 2, kq = t & 3;
    const int col = c0 + cl, h = col >> 6, n = col & 63;
    f16 tmp[16];
    #pragma unroll
    for (int j = 0; j < 16; ++j) tmp[j] = (f16)tile[kq*16 + j][cl];
    f16* dst = WC + (size_t)(h*128 + n)*256 + k0 + kq*16;
    *(f16x8*)dst       = *(f16x8*)&tmp[0];
    *(f16x8*)(dst + 8) = *(f16x8*)&tmp[8];
  } else if (b < 96) {                     // Wxs rows
    const int bb = b - 32;
    const int h = bb >> 3, k0 = (bb & 7) * 32;
    const int k = t & 31, sq = t >> 5;     // 8 s-values per thread
    float accs[8];
    #pragma unroll
    for (int j = 0; j < 8; ++j) accs[j] = 0.f;
    for (int d = 0; d < 64; ++d) {
      float a = Wx[(size_t)(k0 + k)*512 + h*64 + d];
      #pragma unroll
      for (int j = 0; j < 8; ++j) accs[j] += a * Wsl[d*64 + sq*8 + j];
    }
    #pragma unroll
    for (int j = 0; j < 8; ++j)
      WC[(size_t)(h*128 + 64 + sq*8 + j)*256 + k0 + k] = (f16)accs[j];
  } else if (b == 96) {                    // bsp[h][s]
    for (int u = t; u < 512; u += 256) {
      int h = u >> 6, s = u & 63;
      float a = bsl[s];
      for (int d = 0; d < 64; ++d) a += bx[h*64 + d] * Wsl[d*64 + s];
      bsp[h*64 + s] = a;
    }
  } else {                                 // zero Tg + normg
    float4 z; z.x = z.y = z.z = z.w = 0.f;
    ((float4*)Tz)[(b - 97) * 256 + t] = z;
  }
}

// Round-0 per-thread ordering (112 VGPR, no spill) with two changes:
// (1) kb-parity double-buffered staging -> the WAR barrier between consecutive
//     kb-steps disappears: ONE barrier per kb (24/block vs 40).
// (2) all main-loop barriers are wave_bar() (lgkm-only drain) -> next-tile
//     global loads issued at kb t stay in flight across the barrier and the
//     MFMAs of tile t, draining only at the kb t+1 stores (compiler-inserted
//     vmcnt wait at the use site).
// Cross-wave ordering proof: every barrier is preceded by each wave's
// lgkmcnt(0); fragment reads of buf p at kb t are retired before that wave's
// barrier at kb t+1 (MFMA use forces the wait), and the next write to buf p is
// at kb t+2, behind that barrier. Epilogue alias (fxT/wT = X1/W1): kb3 reads
// drain before epilogue-bar; Phase-C reads drain before next m0's kb0 bar;
// kb1 (first write to X1/W1) is behind it.
// LDS 4 x 18432 = 73728 B -> 2 blocks/CU (measured runtime concurrency at the
// 36864-B config was only ~1.7 blocks/CU, so little is lost statically).
__global__ __launch_bounds__(256, 2)
void fused_main(const float* __restrict__ x,   const float* __restrict__ bfx,
                const float* __restrict__ bsp, const float* __restrict__ temp,
                const f16* __restrict__ WC,    float* __restrict__ Tg,
                float* __restrict__ normg) {
  __shared__ alignas(16) char smem[4 * 128 * LDX * 2];   // 73728 B
  f16* X0 = (f16*)smem;                    // x staging, even tiles
  f16* W0 = X0 + 128 * LDX;                // W staging, even tiles
  f16* X1 = W0 + 128 * LDX;                // x staging, odd tiles | alias fx^T [64][LDT]
  f16* W1 = X1 + 128 * LDX;                // W staging, odd tiles | alias w^T  [64][LDT]
  f16* sm_fxT = X1;                        // 64*136*2 = 17408 <= 18432 B region
  f16* sm_wT  = W1;

  // XCD swizzle: all 8 heads of a chunk on one XCD
  const int j    = blockIdx.x;
  const int xcd  = j & 7, slot = j >> 3;
  const int chunk = xcd * 32 + (slot >> 3);
  const int h     = slot & 7;

  const int tid = threadIdx.x;
  const int wv = tid >> 6, lane = tid & 63, quad = lane >> 4, ln = lane & 15;
  const int wm = wv >> 1, wn = wv & 1;
  const long tokBase = (long)chunk * CHUNK;
  const int b  = (int)(tokBase >> 16);
  const int bh = b * Hc + h;

  const float tc = fminf(fmaxf(temp[h], 0.5f), 5.0f);
  const float k2 = 1.44269504f / tc;

  float bv[4];
  {
    const float* bb = (wn == 0) ? (bfx + h*64) : (bsp + h*64);
    #pragma unroll
    for (int nt = 0; nt < 4; ++nt) bv[nt] = bb[nt*16 + ln];
  }

  f32x4 Tacc[2][2];
  #pragma unroll
  for (int i = 0; i < 2; ++i) { Tacc[i][0] = splat4(0.f); Tacc[i][1] = splat4(0.f); }
  float nacc[4] = {0.f, 0.f, 0.f, 0.f};
  const int ci = wv >> 1, cj = wv & 1;

  const f16* WCh = WC + (size_t)h * 128 * 256;

  const int r0 = tid >> 2, seg = tid & 3;
  const int wrow = tid >> 1, whalf = tid & 1;

  float4 xr[8]; f16x8 wr[4];
  auto loadx = [&](int m0, int kb) {
    const float* p = x + (tokBase + (long)m0*128 + r0)*Cc + kb*64 + seg*16;
    xr[0] = *(const float4*)p;        xr[1] = *(const float4*)(p + 4);
    xr[2] = *(const float4*)(p + 8);  xr[3] = *(const float4*)(p + 12);
    p += 64 * Cc;
    xr[4] = *(const float4*)p;        xr[5] = *(const float4*)(p + 4);
    xr[6] = *(const float4*)(p + 8);  xr[7] = *(const float4*)(p + 12);
  };
  auto loadw = [&](int kb) {
    const f16* p = WCh + wrow*256 + kb*64 + whalf*32;
    wr[0] = *(const f16x8*)p;         wr[1] = *(const f16x8*)(p + 8);
    wr[2] = *(const f16x8*)(p + 16);  wr[3] = *(const f16x8*)(p + 24);
  };

  loadx(0, 0); loadw(0);

  for (int m0 = 0; m0 < 4; ++m0) {
    // ---------- Phase A: [fx | sp] = x_tile(128x256) @ WC_h(256x128) ----------
    f32x4 acc[4][4];
    #pragma unroll
    for (int mt = 0; mt < 4; ++mt)
      #pragma unroll
      for (int nt = 0; nt < 4; ++nt) acc[mt][nt] = splat4(bv[nt]);

    for (int kb = 0; kb < 4; ++kb) {
      const int t = m0*4 + kb;
      f16* sx = (t & 1) ? X1 : X0;
      f16* sw = (t & 1) ? W1 : W0;
      // stores of tile t (compiler inserts the vmcnt wait for xr/wr here)
      *(f16x8*)&sx[r0*LDX + seg*16]          = pack8(xr[0], xr[1]);
      *(f16x8*)&sx[r0*LDX + seg*16 + 8]      = pack8(xr[2], xr[3]);
      *(f16x8*)&sx[(r0+64)*LDX + seg*16]     = pack8(xr[4], xr[5]);
      *(f16x8*)&sx[(r0+64)*LDX + seg*16 + 8] = pack8(xr[6], xr[7]);
      *(f16x8*)&sw[wrow*LDX + whalf*32]      = wr[0];
      *(f16x8*)&sw[wrow*LDX + whalf*32 +  8] = wr[1];
      *(f16x8*)&sw[wrow*LDX + whalf*32 + 16] = wr[2];
      *(f16x8*)&sw[wrow*LDX + whalf*32 + 24] = wr[3];
      { int nt_ = t + 1;
        if (nt_ < 16) { loadx(nt_ >> 2, nt_ & 3); loadw(nt_ & 3); } }
      wave_bar();                          // writes visible; loads stay in flight
      #pragma unroll
      for (int ks = 0; ks < 2; ++ks) {
        f16x8 af[4], bf[4];
        #pragma unroll
        for (int mt = 0; mt < 4; ++mt)
          af[mt] = *(const f16x8*)&sx[(wm*64 + mt*16 + ln)*LDX + ks*32 + quad*8];
        #pragma unroll
        for (int nt = 0; nt < 4; ++nt)
          bf[nt] = *(const f16x8*)&sw[(wn*64 + nt*16 + ln)*LDX + ks*32 + quad*8];
        #pragma unroll
        for (int mt = 0; mt < 4; ++mt)
          #pragma unroll
          for (int nt = 0; nt < 4; ++nt)
            acc[mt][nt] = MFMA(af[mt], bf[nt], acc[mt][nt]);
      }
    }
    wave_bar();                            // kb3 reads of X1/W1 done -> alias rewrite ok

    // ---------- epilogue into aliased buffers ----------
    if (wn == 0) {
      #pragma unroll
      for (int mt = 0; mt < 4; ++mt)
        #pragma unroll
        for (int nt = 0; nt < 4; ++nt) {
          f16x4 v = { (f16)acc[mt][nt][0], (f16)acc[mt][nt][1],
                      (f16)acc[mt][nt][2], (f16)acc[mt][nt][3] };
          *(f16x4*)&sm_fxT[(nt*16 + ln)*LDT + wm*64 + mt*16 + quad*4] = v;
        }
    } else {
      #pragma unroll
      for (int mt = 0; mt < 4; ++mt) {
        float e[4][4], wout[4][4];
        #pragma unroll
        for (int nt = 0; nt < 4; ++nt)
          #pragma unroll
          for (int rg = 0; rg < 4; ++rg)
            e[nt][rg] = exp2f(acc[mt][nt][rg] * k2);   // no max-sub: logits bounded
        #pragma unroll
        for (int rg = 0; rg < 4; ++rg) {
          float rs = e[0][rg] + e[1][rg] + e[2][rg] + e[3][rg];
          #pragma unroll
          for (int dd = 1; dd < 16; dd <<= 1) rs += __shfl_xor(rs, dd, 64);
          float inv = 1.0f / rs;
          #pragma unroll
          for (int nt = 0; nt < 4; ++nt) {
            wout[nt][rg] = e[nt][rg] * inv;
            nacc[nt] += wout[nt][rg];
          }
        }
        #pragma unroll
        for (int nt = 0; nt < 4; ++nt) {
          f16x4 v = { (f16)wout[nt][0], (f16)wout[nt][1],
                      (f16)wout[nt][2], (f16)wout[nt][3] };
          *(f16x4*)&sm_wT[(nt*16 + ln)*LDT + wm*64 + mt*16 + quad*4] = v;
        }
      }
    }
    wave_bar();                            // epilogue writes visible

    // ---------- Phase C: T[s][d] += w^T @ fx, K=128 ----------
    #pragma unroll
    for (int ks = 0; ks < 4; ++ks) {
      f16x8 a0 = *(const f16x8*)&sm_wT [(ci*32 +      ln)*LDT + ks*32 + quad*8];
      f16x8 a1 = *(const f16x8*)&sm_wT [(ci*32 + 16 + ln)*LDT + ks*32 + quad*8];
      f16x8 b0 = *(const f16x8*)&sm_fxT[(cj*32 +      ln)*LDT + ks*32 + quad*8];
      f16x8 b1 = *(const f16x8*)&sm_fxT[(cj*32 + 16 + ln)*LDT + ks*32 + quad*8];
      Tacc[0][0] = MFMA(a0, b0, Tacc[0][0]);
      Tacc[0][1] = MFMA(a0, b1, Tacc[0][1]);
      Tacc[1][0] = MFMA(a1, b0, Tacc[1][0]);
      Tacc[1][1] = MFMA(a1, b1, Tacc[1][1]);
    }
    // Phase-C reads drain (lgkmcnt) before next m0's kb0 barrier; first write
    // to the aliased X1/W1 is kb1, behind that barrier.
  }

  // ---------- flush ----------
  float* Tb = Tg + bh * 4096;
  #pragma unroll
  for (int mt2 = 0; mt2 < 2; ++mt2)
    #pragma unroll
    for (int nt2 = 0; nt2 < 2; ++nt2)
      #pragma unroll
      for (int rg = 0; rg < 4; ++rg) {
        int s = ci*32 + mt2*16 + quad*4 + rg;
        int d = cj*32 + nt2*16 + ln;
        atomicAdd(&Tb[s*64 + d], Tacc[mt2][nt2][rg]);
      }
  if (wn == 1) {
    #pragma unroll
    for (int nt = 0; nt < 4; ++nt) {
      float v = nacc[nt];
      v += __shfl_xor(v, 16, 64);
      v += __shfl_xor(v, 32, 64);
      if (lane < 16) atomicAdd(&normg[bh*64 + nt*16 + ln], v);
    }
  }
}

__global__ void finalize(const float* __restrict__ Tg, const float* __restrict__ normg,
                         float* __restrict__ out) {
  int i = blockIdx.x * 256 + threadIdx.x;
  out[i] = Tg[i] / (normg[i >> 6] + 0.01f);
}

extern "C" void kernel_launch(void* const* d_in, const int* in_sizes, int n_in,
                              void* d_out, int out_size, void* d_ws, size_t ws_size,
                              hipStream_t stream) {
  const float* x    = (const float*)d_in[0];
  const float* Wx   = (const float*)d_in[1];
  const float* bx   = (const float*)d_in[2];
  const float* Wfx  = (const float*)d_in[3];
  const float* bfx  = (const float*)d_in[4];
  const float* Wsl  = (const float*)d_in[5];
  const float* bsl  = (const float*)d_in[6];
  const float* temp = (const float*)d_in[7];
  float* out = (float*)d_out;

  float* Tg    = (float*)d_ws;
  float* normg = Tg + 16 * 4096;
  f16*   WC    = (f16*)((char*)d_ws + 266240);
  float* bsp   = (float*)((char*)d_ws + 790528);

  prep_a    <<<162, 256, 0, stream>>>(Wx, Wfx, Wsl, bx, bsl, WC, bsp, Tg);
  fused_main<<<2048, 256, 0, stream>>>(x, bfx, bsp, temp, WC, Tg, normg);
  finalize  <<<256, 256, 0, stream>>>(Tg, normg, out);
}